// Round 6
// baseline (407.136 us; speedup 1.0000x reference)
//
#include <hip/hip_runtime.h>
#include <math.h>

// Problem constants
#define NROWS 16384   // 32*512
#define H     768
#define KEXP  6912    // 768 (silu*base_w) + 768*8 (bases*spline_w*scaler)
#define NCHUNK 108    // KEXP/64 K-steps
#define NITER 54      // 2 K-steps per iteration

typedef __attribute__((ext_vector_type(8))) short  bhalf8;
typedef __attribute__((ext_vector_type(4))) float  floatx4;

__device__ __forceinline__ unsigned short f2bf(float f) {
    unsigned int u = __float_as_uint(f);
    u = (u + 0x7FFFu + ((u >> 16) & 1u)) >> 16;   // RNE
    return (unsigned short)u;
}
__device__ __forceinline__ float bf2f(unsigned short h) {
    return __uint_as_float(((unsigned int)h) << 16);
}
__device__ __forceinline__ unsigned int pack2(unsigned short a, unsigned short b) {
    return (unsigned int)a | ((unsigned int)b << 16);
}
__device__ __forceinline__ float silu_f(float x) { return x / (1.0f + __expf(-x)); }

// Branch-free tanh-form GELU (|err vs exact erf-GELU| < ~1e-3 in u)
__device__ __forceinline__ float gelu_fast(float x) {
    float x3 = x * x * x;
    float y = fmaf(x3, 0.0356774081f, x * 0.7978845608f);
    float e = __expf(2.0f * y);
    float th = 1.0f - 2.0f / (e + 1.0f);
    return 0.5f * x * (1.0f + th);
}

// Closed-form cubic B-spline bases on uniform knots g[j] = (j-3)*0.4 - 1.
__device__ __forceinline__ void kan_bases(float x, float* __restrict__ b) {
    const float c6 = 0.166666666667f;
    float u  = fmaf(x, 2.5f, 5.5f);
    float fj = floorf(u);
    float t  = u - fj;
    int  j0  = (int)fj;
    float t2 = t * t, t3 = t2 * t;
    float n0 = t3 * c6;
    float n1 = fmaf(t3, -0.5f, fmaf(t2, 0.5f, fmaf(t, 0.5f, c6)));
    float n2 = fmaf(t3, 0.5f, fmaf(t2, -1.0f, 0.666666666667f));
    float omt = 1.0f - t;
    float n3 = omt * omt * omt * c6;
#pragma unroll
    for (int c = 0; c < 8; ++c) {
        int d = j0 - c;
        float v = (d == 0) ? n0 : 0.0f;
        v = (d == 1) ? n1 : v;
        v = (d == 2) ? n2 : v;
        v = (d == 3) ? n3 : v;
        b[c] = v;
    }
}

// ---- prep_expand (flat, float4): blocks 0..6143 expand F — 2048 elems/block,
//      8 elems/thread as 2x float4 (16B reads; 8B silu + 64B bases stores, all
//      lane-consecutive; a 4-run never crosses a row since 768%4==0).
//      Blocks 6144..6911: W' rows (round-2 code verbatim).
__global__ __launch_bounds__(256) void prep_expand(
    const float* __restrict__ x, const float* __restrict__ bw,
    const float* __restrict__ sw, const float* __restrict__ sc,
    unsigned short* __restrict__ wp, unsigned short* __restrict__ F)
{
    const int b = blockIdx.x, t = threadIdx.x;
    if (b < 6144) {
#pragma unroll
        for (int j = 0; j < 2; ++j) {
            const int e = b * 2048 + j * 1024 + t * 4;
            const int n = e / 768;                 // magic-mul
            const int i = e - n * 768;             // i%4==0
            float4 xv = *(const float4*)(x + e);
            unsigned short* out = F + (size_t)n * KEXP;
            uint2 sp;
            sp.x = pack2(f2bf(silu_f(xv.x)), f2bf(silu_f(xv.y)));
            sp.y = pack2(f2bf(silu_f(xv.z)), f2bf(silu_f(xv.w)));
            *(uint2*)(out + i) = sp;               // 8B store
            float b0[8], b1[8], b2[8], b3[8];
            kan_bases(xv.x, b0); kan_bases(xv.y, b1);
            kan_bases(xv.z, b2); kan_bases(xv.w, b3);
            unsigned short* ob = out + H + (size_t)i * 8;
            uint4 p0, p1, p2, p3;
            p0.x = pack2(f2bf(b0[0]), f2bf(b0[1])); p0.y = pack2(f2bf(b0[2]), f2bf(b0[3]));
            p0.z = pack2(f2bf(b0[4]), f2bf(b0[5])); p0.w = pack2(f2bf(b0[6]), f2bf(b0[7]));
            p1.x = pack2(f2bf(b1[0]), f2bf(b1[1])); p1.y = pack2(f2bf(b1[2]), f2bf(b1[3]));
            p1.z = pack2(f2bf(b1[4]), f2bf(b1[5])); p1.w = pack2(f2bf(b1[6]), f2bf(b1[7]));
            p2.x = pack2(f2bf(b2[0]), f2bf(b2[1])); p2.y = pack2(f2bf(b2[2]), f2bf(b2[3]));
            p2.z = pack2(f2bf(b2[4]), f2bf(b2[5])); p2.w = pack2(f2bf(b2[6]), f2bf(b2[7]));
            p3.x = pack2(f2bf(b3[0]), f2bf(b3[1])); p3.y = pack2(f2bf(b3[2]), f2bf(b3[3]));
            p3.z = pack2(f2bf(b3[4]), f2bf(b3[5])); p3.w = pack2(f2bf(b3[6]), f2bf(b3[7]));
            *(uint4*)(ob +  0) = p0;               // 64B contiguous
            *(uint4*)(ob +  8) = p1;
            *(uint4*)(ob + 16) = p2;
            *(uint4*)(ob + 24) = p3;
        }
    } else {
        const int n = b - 6144;
        const float* bwr = bw + (size_t)n * H;
        unsigned short* out = wp + (size_t)n * KEXP;
        if (t < 96) {
            const float4* xp = (const float4*)(bwr + t * 8);
            float4 v0 = xp[0], v1 = xp[1];
            uint4 pk;
            pk.x = pack2(f2bf(v0.x), f2bf(v0.y));
            pk.y = pack2(f2bf(v0.z), f2bf(v0.w));
            pk.z = pack2(f2bf(v1.x), f2bf(v1.y));
            pk.w = pack2(f2bf(v1.z), f2bf(v1.w));
            *(uint4*)(out + t * 8) = pk;
        }
#pragma unroll
        for (int p = 0; p < 3; ++p) {
            int i = t + p * 256;
            float s = sc[(size_t)n * H + i];
            const float4* swp = (const float4*)(sw + ((size_t)n * H + i) * 8);
            float4 w0 = swp[0], w1 = swp[1];
            uint4 pk;
            pk.x = pack2(f2bf(w0.x * s), f2bf(w0.y * s));
            pk.y = pack2(f2bf(w0.z * s), f2bf(w0.w * s));
            pk.z = pack2(f2bf(w1.x * s), f2bf(w1.y * s));
            pk.w = pack2(f2bf(w1.z * s), f2bf(w1.w * s));
            *(uint4*)(out + H + (size_t)i * 8) = pk;
        }
    }
}

// ==== Layer 1: 256x192 GEMM — ROUND-2 SCHEDULE VERBATIM (measured 157us,
// MfmaUtil 48%, 0 conflicts). 4 phases/K-step, A-frags register-resident across
// the K-step (22 ds_read/K-step), counted vmcnt {10,10,11,8,-,10,11,8}.
// r5 taught: fewer/bigger phases regress (18-deep ds_read burst before one
// lgkmcnt(0) serializes worse than a barrier). Do not touch.

#define AS1 __attribute__((address_space(1)))
#define AS3 __attribute__((address_space(3)))

#define DSR(D, A, O) asm volatile("ds_read_b128 %0, %1 offset:" #O : "=v"(D) : "v"(A) : "memory")
#define LDA0(O) do{ DSR(fA0[0],avA[0],O); DSR(fA0[1],avA[1],O); DSR(fA0[2],avA[2],O); DSR(fA0[3],avA[3],O); \
                    DSR(fA0[4],avA[4],O); DSR(fA0[5],avA[5],O); DSR(fA0[6],avA[6],O); DSR(fA0[7],avA[7],O); }while(0)
#define LDA1(O) do{ DSR(fA1[0],avA[0],O); DSR(fA1[1],avA[1],O); DSR(fA1[2],avA[2],O); DSR(fA1[3],avA[3],O); \
                    DSR(fA1[4],avA[4],O); DSR(fA1[5],avA[5],O); DSR(fA1[6],avA[6],O); DSR(fA1[7],avA[7],O); }while(0)
#define LDB(O)  do{ DSR(fB[0],avB[0],O); DSR(fB[1],avB[1],O); }while(0)

#define MM0(QN) do{ \
    _Pragma("unroll") \
    for (int kk = 0; kk < 2; ++kk) \
        _Pragma("unroll") \
        for (int im = 0; im < 4; ++im) \
            acc0[QN][im] = __builtin_amdgcn_mfma_f32_16x16x32_bf16( \
                fA0[im*2+kk], fB[kk], acc0[QN][im], 0, 0, 0); \
}while(0)
#define MM1(QN) do{ \
    _Pragma("unroll") \
    for (int kk = 0; kk < 2; ++kk) \
        _Pragma("unroll") \
        for (int im = 0; im < 4; ++im) \
            acc1[QN][im] = __builtin_amdgcn_mfma_f32_16x16x32_bf16( \
                fA1[im*2+kk], fB[kk], acc1[QN][im], 0, 0, 0); \
}while(0)

#define STG_A(BF,HH,KS) do{ \
    __builtin_amdgcn_global_load_lds((const AS1 void*)(pA##HH[0] + (size_t)(KS)*64), \
        (AS3 void*)&sA[BF][HH][wb8], 16, 0, 0); \
    __builtin_amdgcn_global_load_lds((const AS1 void*)(pA##HH[1] + (size_t)(KS)*64), \
        (AS3 void*)&sA[BF][HH][4096 + wb8], 16, 0, 0); \
}while(0)
#define STG_B(BF,QN,KS) \
    __builtin_amdgcn_global_load_lds((const AS1 void*)(pB[QN] + (size_t)(KS)*64), \
        (AS3 void*)&sB[BF][QN][wb8], 16, 0, 0)

#define PH_MID do{ __builtin_amdgcn_s_barrier(); \
    asm volatile("s_waitcnt lgkmcnt(0)" ::: "memory"); \
    __builtin_amdgcn_sched_barrier(0); \
    __builtin_amdgcn_s_setprio(1); }while(0)
#define PH_END do{ __builtin_amdgcn_s_setprio(0); \
    __builtin_amdgcn_sched_barrier(0); \
    __builtin_amdgcn_s_barrier(); }while(0)
#define PH_END_VMN(N) do{ __builtin_amdgcn_s_setprio(0); \
    __builtin_amdgcn_sched_barrier(0); \
    asm volatile("s_waitcnt vmcnt(" #N ")" ::: "memory"); \
    __builtin_amdgcn_s_barrier(); }while(0)

__global__ __launch_bounds__(512, 2) void kan1_gemm(
    const unsigned short* __restrict__ F, const unsigned short* __restrict__ wp,
    unsigned short* __restrict__ l1)
{
    __shared__ __align__(16) unsigned short sA[2][2][8192];  // [buf][half 128rows][128*64]
    __shared__ __align__(16) unsigned short sB[2][3][4096];  // [buf][third 64rows][64*64]

    const int b = blockIdx.x;                  // 0..255
    const int s = b >> 3;
    const int rowT = (b & 7) * 8 + (s >> 2);   // 0..63
    const int colT = s & 3;                    // 0..3
    const int rowBase = rowT * 256, colBase = colT * 192;

    const int t = threadIdx.x;
    const int lane = t & 63;
    const int quad = lane >> 4, lm = lane & 15, p7 = lane & 7;
    const int wv = t >> 6, wr = wv & 1, wc = wv >> 1;   // 2M x 4N wave grid

    const int rr = t >> 3;                    // 0..63
    const int slotx = (t & 7) ^ (rr & 7);
    const int wb8 = (t & 448) * 8;            // wave-uniform LDS elem base (wv*512)

    const unsigned short* pA0[2]; const unsigned short* pA1[2];
    const unsigned short* pB[3];
#pragma unroll
    for (int p = 0; p < 2; ++p) {
        pA0[p] = F + (size_t)(rowBase +       p*64 + rr) * KEXP + slotx*8;
        pA1[p] = F + (size_t)(rowBase + 128 + p*64 + rr) * KEXP + slotx*8;
    }
#pragma unroll
    for (int q = 0; q < 3; ++q)
        pB[q] = wp + (size_t)(colBase + q*64 + rr) * KEXP + slotx*8;

    unsigned int avA[8], avB[2];
    {
        unsigned int aB = (unsigned int)(size_t)(AS3 unsigned short*)&sA[0][0][0];
        unsigned int bB = (unsigned int)(size_t)(AS3 unsigned short*)&sB[0][0][0];
#pragma unroll
        for (int im = 0; im < 4; ++im)
#pragma unroll
            for (int kk = 0; kk < 2; ++kk)
                avA[im*2+kk] = aB + (unsigned)(((wr*64 + im*16 + lm)*64 + (((kk*4+quad)^p7)*8)) * 2);
#pragma unroll
        for (int kk = 0; kk < 2; ++kk)
            avB[kk] = bB + (unsigned)(((wc*16 + lm)*64 + (((kk*4+quad)^p7)*8)) * 2);
    }

    floatx4 acc0[3][4] = {};   // [qn][im], qm=0 rows
    floatx4 acc1[3][4] = {};   // qm=1 rows
    bhalf8 fA0[8], fA1[8], fB[2];

    // prologue: buf0 <- ks0 (7 loads), buf1 <- ks1 minus B2 (6 loads); retire 5
    STG_A(0,0,0); STG_A(0,1,0); STG_B(0,0,0); STG_B(0,1,0); STG_B(0,2,0);
    STG_A(1,0,1); STG_A(1,1,1); STG_B(1,0,1); STG_B(1,1,1);
    asm volatile("s_waitcnt vmcnt(8)" ::: "memory");
    __builtin_amdgcn_s_barrier();

#pragma unroll 1
    for (int i = 0; i < NITER; ++i) {
        const int k1 = 2*i + 1;
        const int k2 = (2*i + 2 > 107) ? 107 : 2*i + 2;
        const int k3 = (2*i + 3 > 107) ? 107 : 2*i + 3;
        // K-step 2i from buf0
        LDA0(0);     LDB(0);     STG_B(1,2,k1);               PH_MID; MM0(0);         PH_END_VMN(10);
        LDA1(16384);             STG_A(0,0,k2);               PH_MID; MM1(0);         PH_END_VMN(10);
        LDB(8192);               STG_A(0,1,k2);               PH_MID; MM1(1); MM0(1); PH_END_VMN(11);
        LDB(16384);              STG_B(0,0,k2); STG_B(0,1,k2);PH_MID; MM0(2); MM1(2); PH_END_VMN(8);
        // K-step 2i+1 from buf1
        LDA0(32768); LDB(24576); STG_B(0,2,k2);               PH_MID; MM0(0);         PH_END;
        LDA1(49152);             STG_A(1,0,k3);               PH_MID; MM1(0);         PH_END_VMN(10);
        LDB(32768);              STG_A(1,1,k3);               PH_MID; MM1(1); MM0(1); PH_END_VMN(11);
        LDB(40960);              STG_B(1,0,k3); STG_B(1,1,k3);PH_MID; MM0(2); MM1(2); PH_END_VMN(8);
    }

    // epilogue: C layout col=lane&15, row=quad*4+reg
#pragma unroll
    for (int qn = 0; qn < 3; ++qn)
#pragma unroll
    for (int im = 0; im < 4; ++im) {
        const int col = colBase + qn*64 + wc*16 + lm;
        {
            const int row0 = rowBase + wr*64 + im*16 + quad*4;
#pragma unroll
            for (int rg = 0; rg < 4; ++rg)
                l1[(size_t)(row0 + rg) * H + col] = f2bf(acc0[qn][im][rg]);
        }
        {
            const int row0 = rowBase + 128 + wr*64 + im*16 + quad*4;
#pragma unroll
            for (int rg = 0; rg < 4; ++rg)
                l1[(size_t)(row0 + rg) * H + col] = f2bf(acc1[qn][im][rg]);
        }
    }
}

// ---- Layer 2: LDS-staged pre-scaled bf16 weights, 16 rows/block (1024 blocks).
// Cuts the 805 MB/dispatch L2 weight stream to ~50 MB. Validated in round 3
// (passed, absmax 0.125). sW: 16B/lane b128 reads conflict-free; sB2: 4B/lane.
#define R2 16
__global__ __launch_bounds__(256) void kan2_kernel(
    const unsigned short* __restrict__ l1, const float* __restrict__ bw,
    const float* __restrict__ sw, const float* __restrict__ sc,
    float* __restrict__ out)
{
    __shared__ __align__(16) unsigned short sW[2 * H * 8];   // 24.6 KB bf16 (sc folded)
    __shared__ unsigned int sB2[H];                          // 3 KB packed bf16 pairs

    const int t = threadIdx.x;
#pragma unroll
    for (int c = 0; c < 6; ++c) {
        int idx = t + c * 256;                 // 0..1535: o = idx/H, i = idx%H
        int o = (idx >= H) ? 1 : 0;
        int i = idx - o * H;
        float s = sc[(size_t)o * H + i];
        const float4* q = (const float4*)(sw + ((size_t)o * H + i) * 8);
        float4 w0 = q[0], w1 = q[1];
        uint4 pk;
        pk.x = pack2(f2bf(w0.x * s), f2bf(w0.y * s));
        pk.y = pack2(f2bf(w0.z * s), f2bf(w0.w * s));
        pk.z = pack2(f2bf(w1.x * s), f2bf(w1.y * s));
        pk.w = pack2(f2bf(w1.z * s), f2bf(w1.w * s));
        *(uint4*)&sW[(size_t)idx * 8] = pk;
    }
#pragma unroll
    for (int c = 0; c < 3; ++c) {
        int i = t + c * 256;
        sB2[i] = pack2(f2bf(bw[i]), f2bf(bw[H + i]));
    }
    __syncthreads();

    const int lane = t & 63;
    const int wv = t >> 6;
#pragma unroll 1
    for (int r = 0; r < 4; ++r) {
        const int n = blockIdx.x * R2 + wv * 4 + r;
        float a0 = 0.f, a1 = 0.f;
#pragma unroll
        for (int ii = 0; ii < H / 64; ++ii) {
            int i = lane + ii * 64;
            float h = bf2f(l1[(size_t)n * H + i]);
            float u = gelu_fast(h);
            float f0 = silu_f(u);
            float bb[8];
            kan_bases(u, bb);
            unsigned int bp = sB2[i];
            float bw0 = bf2f((unsigned short)(bp & 0xffffu));
            float bw1 = bf2f((unsigned short)(bp >> 16));
            bhalf8 w0 = *(const bhalf8*)&sW[(size_t)i * 8];
            bhalf8 w1 = *(const bhalf8*)&sW[(size_t)(H + i) * 8];
            float t0 = 0.f, t1 = 0.f;
#pragma unroll
            for (int c = 0; c < 8; ++c) {
                t0 = fmaf(bb[c], bf2f((unsigned short)w0[c]), t0);
                t1 = fmaf(bb[c], bf2f((unsigned short)w1[c]), t1);
            }
            a0 += fmaf(f0, bw0, t0);
            a1 += fmaf(f0, bw1, t1);
        }
#pragma unroll
        for (int off = 32; off > 0; off >>= 1) {
            a0 += __shfl_down(a0, off, 64);
            a1 += __shfl_down(a1, off, 64);
        }
        if (lane == 0) {
            out[(size_t)n * 2 + 0] = a0;
            out[(size_t)n * 2 + 1] = a1;
        }
    }
}

extern "C" void kernel_launch(void* const* d_in, const int* in_sizes, int n_in,
                              void* d_out, int out_size, void* d_ws, size_t ws_size,
                              hipStream_t stream) {
    const float* hidden = (const float*)d_in[0];
    const float* bw1    = (const float*)d_in[1];
    const float* sw1    = (const float*)d_in[2];
    const float* sc1    = (const float*)d_in[3];
    const float* bw2    = (const float*)d_in[4];
    const float* sw2    = (const float*)d_in[5];
    const float* sc2    = (const float*)d_in[6];
    float* out = (float*)d_out;

    const size_t l1_elems = (size_t)NROWS * H;     // 25.2 MB bf16
    const size_t wp_elems = (size_t)H * KEXP;      // 10.6 MB bf16
    unsigned short* l1 = (unsigned short*)d_ws;
    unsigned short* wp = l1 + l1_elems;
    unsigned short* F  = wp + wp_elems;            // 226.5 MB bf16

    prep_expand<<<6144 + H, 256, 0, stream>>>(hidden, bw1, sw1, sc1, wp, F);
    kan1_gemm<<<256, 512, 0, stream>>>(F, wp, l1);
    kan2_kernel<<<NROWS / R2, 256, 0, stream>>>(l1, bw2, sw2, sc2, out);
}

// Round 7
// 332.541 us; speedup vs baseline: 1.2243x; 1.2243x over previous
//
#include <hip/hip_runtime.h>
#include <math.h>

// Problem constants
#define NROWS 16384   // 32*512
#define H     768
#define KEXP  6912    // 768 (silu*base_w) + 768*8 (bases*spline_w*scaler)
#define NCHUNK 108    // KEXP/64 K-steps
#define NITER 54      // 2 K-steps per iteration

typedef __attribute__((ext_vector_type(8))) short  bhalf8;
typedef __attribute__((ext_vector_type(4))) float  floatx4;

__device__ __forceinline__ unsigned short f2bf(float f) {
    unsigned int u = __float_as_uint(f);
    u = (u + 0x7FFFu + ((u >> 16) & 1u)) >> 16;   // RNE
    return (unsigned short)u;
}
__device__ __forceinline__ float bf2f(unsigned short h) {
    return __uint_as_float(((unsigned int)h) << 16);
}
__device__ __forceinline__ unsigned int pack2(unsigned short a, unsigned short b) {
    return (unsigned int)a | ((unsigned int)b << 16);
}
__device__ __forceinline__ float silu_f(float x) { return x / (1.0f + __expf(-x)); }

// Branch-free tanh-form GELU (|err vs exact erf-GELU| < ~1e-3 in u)
__device__ __forceinline__ float gelu_fast(float x) {
    float x3 = x * x * x;
    float y = fmaf(x3, 0.0356774081f, x * 0.7978845608f);
    float e = __expf(2.0f * y);
    float th = 1.0f - 2.0f / (e + 1.0f);
    return 0.5f * x * (1.0f + th);
}

// Closed-form cubic B-spline bases on uniform knots g[j] = (j-3)*0.4 - 1.
__device__ __forceinline__ void kan_bases(float x, float* __restrict__ b) {
    const float c6 = 0.166666666667f;
    float u  = fmaf(x, 2.5f, 5.5f);
    float fj = floorf(u);
    float t  = u - fj;
    int  j0  = (int)fj;
    float t2 = t * t, t3 = t2 * t;
    float n0 = t3 * c6;
    float n1 = fmaf(t3, -0.5f, fmaf(t2, 0.5f, fmaf(t, 0.5f, c6)));
    float n2 = fmaf(t3, 0.5f, fmaf(t2, -1.0f, 0.666666666667f));
    float omt = 1.0f - t;
    float n3 = omt * omt * omt * c6;
#pragma unroll
    for (int c = 0; c < 8; ++c) {
        int d = j0 - c;
        float v = (d == 0) ? n0 : 0.0f;
        v = (d == 1) ? n1 : v;
        v = (d == 2) ? n2 : v;
        v = (d == 3) ? n3 : v;
        b[c] = v;
    }
}

// ---- prep_expand (flat, scalar — ROUND-5 MEASURED-BEST): blocks 0..6143
//      expand F (2048 elems/block, 8 STRIDED elems/thread -> every store
//      lane-consecutive/coalesced; no LDS, no syncthreads).
//      Blocks 6144..6911: W' rows (round-2 code verbatim).
//      NOTE r6 lesson: per-thread-contiguous float4 variant breaks cross-lane
//      store coalescing (64B lane stride) and regressed — keep strided form.
__global__ __launch_bounds__(256) void prep_expand(
    const float* __restrict__ x, const float* __restrict__ bw,
    const float* __restrict__ sw, const float* __restrict__ sc,
    unsigned short* __restrict__ wp, unsigned short* __restrict__ F)
{
    const int b = blockIdx.x, t = threadIdx.x;
    if (b < 6144) {
        const int e0 = b * 2048 + t;
#pragma unroll
        for (int j = 0; j < 8; ++j) {
            int e = e0 + j * 256;
            int n = e / 768;                      // magic-mul
            int i = e - n * 768;
            float xv = x[e];                      // x row-major (N,768): linear in e
            unsigned short* out = F + (size_t)n * KEXP;
            out[i] = f2bf(silu_f(xv));            // 2B store, lane-consecutive
            float bb[8];
            kan_bases(xv, bb);
            uint4 pk;
            pk.x = pack2(f2bf(bb[0]), f2bf(bb[1]));
            pk.y = pack2(f2bf(bb[2]), f2bf(bb[3]));
            pk.z = pack2(f2bf(bb[4]), f2bf(bb[5]));
            pk.w = pack2(f2bf(bb[6]), f2bf(bb[7]));
            *(uint4*)(out + H + (size_t)i * 8) = pk;  // 16B store, lane-consecutive
        }
    } else {
        const int n = b - 6144;
        const float* bwr = bw + (size_t)n * H;
        unsigned short* out = wp + (size_t)n * KEXP;
        if (t < 96) {
            const float4* xp = (const float4*)(bwr + t * 8);
            float4 v0 = xp[0], v1 = xp[1];
            uint4 pk;
            pk.x = pack2(f2bf(v0.x), f2bf(v0.y));
            pk.y = pack2(f2bf(v0.z), f2bf(v0.w));
            pk.z = pack2(f2bf(v1.x), f2bf(v1.y));
            pk.w = pack2(f2bf(v1.z), f2bf(v1.w));
            *(uint4*)(out + t * 8) = pk;
        }
#pragma unroll
        for (int p = 0; p < 3; ++p) {
            int i = t + p * 256;
            float s = sc[(size_t)n * H + i];
            const float4* swp = (const float4*)(sw + ((size_t)n * H + i) * 8);
            float4 w0 = swp[0], w1 = swp[1];
            uint4 pk;
            pk.x = pack2(f2bf(w0.x * s), f2bf(w0.y * s));
            pk.y = pack2(f2bf(w0.z * s), f2bf(w0.w * s));
            pk.z = pack2(f2bf(w1.x * s), f2bf(w1.y * s));
            pk.w = pack2(f2bf(w1.z * s), f2bf(w1.w * s));
            *(uint4*)(out + H + (size_t)i * 8) = pk;
        }
    }
}

// ==== Layer 1: 256x192 GEMM — ROUND-2 SCHEDULE VERBATIM (r6-measured 152.6us,
// MfmaUtil 50%, 0 conflicts). 4 phases/K-step, A-frags register-resident across
// the K-step (22 ds_read/K-step), counted vmcnt {10,10,11,8,-,10,11,8}.
// r5 taught: fewer/bigger phases regress. Do not touch.

#define AS1 __attribute__((address_space(1)))
#define AS3 __attribute__((address_space(3)))

#define DSR(D, A, O) asm volatile("ds_read_b128 %0, %1 offset:" #O : "=v"(D) : "v"(A) : "memory")
#define LDA0(O) do{ DSR(fA0[0],avA[0],O); DSR(fA0[1],avA[1],O); DSR(fA0[2],avA[2],O); DSR(fA0[3],avA[3],O); \
                    DSR(fA0[4],avA[4],O); DSR(fA0[5],avA[5],O); DSR(fA0[6],avA[6],O); DSR(fA0[7],avA[7],O); }while(0)
#define LDA1(O) do{ DSR(fA1[0],avA[0],O); DSR(fA1[1],avA[1],O); DSR(fA1[2],avA[2],O); DSR(fA1[3],avA[3],O); \
                    DSR(fA1[4],avA[4],O); DSR(fA1[5],avA[5],O); DSR(fA1[6],avA[6],O); DSR(fA1[7],avA[7],O); }while(0)
#define LDB(O)  do{ DSR(fB[0],avB[0],O); DSR(fB[1],avB[1],O); }while(0)

#define MM0(QN) do{ \
    _Pragma("unroll") \
    for (int kk = 0; kk < 2; ++kk) \
        _Pragma("unroll") \
        for (int im = 0; im < 4; ++im) \
            acc0[QN][im] = __builtin_amdgcn_mfma_f32_16x16x32_bf16( \
                fA0[im*2+kk], fB[kk], acc0[QN][im], 0, 0, 0); \
}while(0)
#define MM1(QN) do{ \
    _Pragma("unroll") \
    for (int kk = 0; kk < 2; ++kk) \
        _Pragma("unroll") \
        for (int im = 0; im < 4; ++im) \
            acc1[QN][im] = __builtin_amdgcn_mfma_f32_16x16x32_bf16( \
                fA1[im*2+kk], fB[kk], acc1[QN][im], 0, 0, 0); \
}while(0)

#define STG_A(BF,HH,KS) do{ \
    __builtin_amdgcn_global_load_lds((const AS1 void*)(pA##HH[0] + (size_t)(KS)*64), \
        (AS3 void*)&sA[BF][HH][wb8], 16, 0, 0); \
    __builtin_amdgcn_global_load_lds((const AS1 void*)(pA##HH[1] + (size_t)(KS)*64), \
        (AS3 void*)&sA[BF][HH][4096 + wb8], 16, 0, 0); \
}while(0)
#define STG_B(BF,QN,KS) \
    __builtin_amdgcn_global_load_lds((const AS1 void*)(pB[QN] + (size_t)(KS)*64), \
        (AS3 void*)&sB[BF][QN][wb8], 16, 0, 0)

#define PH_MID do{ __builtin_amdgcn_s_barrier(); \
    asm volatile("s_waitcnt lgkmcnt(0)" ::: "memory"); \
    __builtin_amdgcn_sched_barrier(0); \
    __builtin_amdgcn_s_setprio(1); }while(0)
#define PH_END do{ __builtin_amdgcn_s_setprio(0); \
    __builtin_amdgcn_sched_barrier(0); \
    __builtin_amdgcn_s_barrier(); }while(0)
#define PH_END_VMN(N) do{ __builtin_amdgcn_s_setprio(0); \
    __builtin_amdgcn_sched_barrier(0); \
    asm volatile("s_waitcnt vmcnt(" #N ")" ::: "memory"); \
    __builtin_amdgcn_s_barrier(); }while(0)

__global__ __launch_bounds__(512, 2) void kan1_gemm(
    const unsigned short* __restrict__ F, const unsigned short* __restrict__ wp,
    unsigned short* __restrict__ l1)
{
    __shared__ __align__(16) unsigned short sA[2][2][8192];  // [buf][half 128rows][128*64]
    __shared__ __align__(16) unsigned short sB[2][3][4096];  // [buf][third 64rows][64*64]

    const int b = blockIdx.x;                  // 0..255
    const int s = b >> 3;
    const int rowT = (b & 7) * 8 + (s >> 2);   // 0..63
    const int colT = s & 3;                    // 0..3
    const int rowBase = rowT * 256, colBase = colT * 192;

    const int t = threadIdx.x;
    const int lane = t & 63;
    const int quad = lane >> 4, lm = lane & 15, p7 = lane & 7;
    const int wv = t >> 6, wr = wv & 1, wc = wv >> 1;   // 2M x 4N wave grid

    const int rr = t >> 3;                    // 0..63
    const int slotx = (t & 7) ^ (rr & 7);
    const int wb8 = (t & 448) * 8;            // wave-uniform LDS elem base (wv*512)

    const unsigned short* pA0[2]; const unsigned short* pA1[2];
    const unsigned short* pB[3];
#pragma unroll
    for (int p = 0; p < 2; ++p) {
        pA0[p] = F + (size_t)(rowBase +       p*64 + rr) * KEXP + slotx*8;
        pA1[p] = F + (size_t)(rowBase + 128 + p*64 + rr) * KEXP + slotx*8;
    }
#pragma unroll
    for (int q = 0; q < 3; ++q)
        pB[q] = wp + (size_t)(colBase + q*64 + rr) * KEXP + slotx*8;

    unsigned int avA[8], avB[2];
    {
        unsigned int aB = (unsigned int)(size_t)(AS3 unsigned short*)&sA[0][0][0];
        unsigned int bB = (unsigned int)(size_t)(AS3 unsigned short*)&sB[0][0][0];
#pragma unroll
        for (int im = 0; im < 4; ++im)
#pragma unroll
            for (int kk = 0; kk < 2; ++kk)
                avA[im*2+kk] = aB + (unsigned)(((wr*64 + im*16 + lm)*64 + (((kk*4+quad)^p7)*8)) * 2);
#pragma unroll
        for (int kk = 0; kk < 2; ++kk)
            avB[kk] = bB + (unsigned)(((wc*16 + lm)*64 + (((kk*4+quad)^p7)*8)) * 2);
    }

    floatx4 acc0[3][4] = {};   // [qn][im], qm=0 rows
    floatx4 acc1[3][4] = {};   // qm=1 rows
    bhalf8 fA0[8], fA1[8], fB[2];

    // prologue: buf0 <- ks0 (7 loads), buf1 <- ks1 minus B2 (6 loads); retire 5
    STG_A(0,0,0); STG_A(0,1,0); STG_B(0,0,0); STG_B(0,1,0); STG_B(0,2,0);
    STG_A(1,0,1); STG_A(1,1,1); STG_B(1,0,1); STG_B(1,1,1);
    asm volatile("s_waitcnt vmcnt(8)" ::: "memory");
    __builtin_amdgcn_s_barrier();

#pragma unroll 1
    for (int i = 0; i < NITER; ++i) {
        const int k1 = 2*i + 1;
        const int k2 = (2*i + 2 > 107) ? 107 : 2*i + 2;
        const int k3 = (2*i + 3 > 107) ? 107 : 2*i + 3;
        // K-step 2i from buf0
        LDA0(0);     LDB(0);     STG_B(1,2,k1);               PH_MID; MM0(0);         PH_END_VMN(10);
        LDA1(16384);             STG_A(0,0,k2);               PH_MID; MM1(0);         PH_END_VMN(10);
        LDB(8192);               STG_A(0,1,k2);               PH_MID; MM1(1); MM0(1); PH_END_VMN(11);
        LDB(16384);              STG_B(0,0,k2); STG_B(0,1,k2);PH_MID; MM0(2); MM1(2); PH_END_VMN(8);
        // K-step 2i+1 from buf1
        LDA0(32768); LDB(24576); STG_B(0,2,k2);               PH_MID; MM0(0);         PH_END;
        LDA1(49152);             STG_A(1,0,k3);               PH_MID; MM1(0);         PH_END_VMN(10);
        LDB(32768);              STG_A(1,1,k3);               PH_MID; MM1(1); MM0(1); PH_END_VMN(11);
        LDB(40960);              STG_B(1,0,k3); STG_B(1,1,k3);PH_MID; MM0(2); MM1(2); PH_END_VMN(8);
    }

    // epilogue: C layout col=lane&15, row=quad*4+reg
#pragma unroll
    for (int qn = 0; qn < 3; ++qn)
#pragma unroll
    for (int im = 0; im < 4; ++im) {
        const int col = colBase + qn*64 + wc*16 + lm;
        {
            const int row0 = rowBase + wr*64 + im*16 + quad*4;
#pragma unroll
            for (int rg = 0; rg < 4; ++rg)
                l1[(size_t)(row0 + rg) * H + col] = f2bf(acc0[qn][im][rg]);
        }
        {
            const int row0 = rowBase + 128 + wr*64 + im*16 + quad*4;
#pragma unroll
            for (int rg = 0; rg < 4; ++rg)
                l1[(size_t)(row0 + rg) * H + col] = f2bf(acc1[qn][im][rg]);
        }
    }
}

// ---- Layer 2: known-good simple version (4 rows/block, wave per row).
// NOT L2-BW-bound: weight stream (805MB) ~23us of L2 BW overlapped under
// heavy VALU (gelu+silu+bases). r3/r6 staged variant added bf16-unpack VALU
// to a VALU-bound kernel and regressed — keep f32 global weight loads.
__global__ __launch_bounds__(256) void kan2_kernel(
    const unsigned short* __restrict__ l1, const float* __restrict__ bw,
    const float* __restrict__ sw, const float* __restrict__ sc,
    float* __restrict__ out)
{
    const int lane = threadIdx.x & 63;
    const int wv = threadIdx.x >> 6;
    const int n = blockIdx.x * 4 + wv;
    float a0 = 0.f, a1 = 0.f;
#pragma unroll
    for (int ii = 0; ii < H / 64; ++ii) {
        int i = lane + ii * 64;
        float h = bf2f(l1[(size_t)n * H + i]);
        float u = gelu_fast(h);
        float f0 = silu_f(u);
        float bb[8];
        kan_bases(u, bb);
        float bw0 = bw[i], bw1 = bw[H + i];
        float s0 = sc[i], s1 = sc[H + i];
        const float4* q0 = (const float4*)(sw + (size_t)i * 8);
        const float4* q1 = (const float4*)(sw + (size_t)(H + i) * 8);
        float4 w00 = q0[0], w01 = q0[1];
        float4 w10 = q1[0], w11 = q1[1];
        float t0 = bb[0]*w00.x + bb[1]*w00.y + bb[2]*w00.z + bb[3]*w00.w
                 + bb[4]*w01.x + bb[5]*w01.y + bb[6]*w01.z + bb[7]*w01.w;
        float t1 = bb[0]*w10.x + bb[1]*w10.y + bb[2]*w10.z + bb[3]*w10.w
                 + bb[4]*w11.x + bb[5]*w11.y + bb[6]*w11.z + bb[7]*w11.w;
        a0 += f0 * bw0 + s0 * t0;
        a1 += f0 * bw1 + s1 * t1;
    }
#pragma unroll
    for (int off = 32; off > 0; off >>= 1) {
        a0 += __shfl_down(a0, off, 64);
        a1 += __shfl_down(a1, off, 64);
    }
    if (lane == 0) {
        out[(size_t)n * 2 + 0] = a0;
        out[(size_t)n * 2 + 1] = a1;
    }
}

extern "C" void kernel_launch(void* const* d_in, const int* in_sizes, int n_in,
                              void* d_out, int out_size, void* d_ws, size_t ws_size,
                              hipStream_t stream) {
    const float* hidden = (const float*)d_in[0];
    const float* bw1    = (const float*)d_in[1];
    const float* sw1    = (const float*)d_in[2];
    const float* sc1    = (const float*)d_in[3];
    const float* bw2    = (const float*)d_in[4];
    const float* sw2    = (const float*)d_in[5];
    const float* sc2    = (const float*)d_in[6];
    float* out = (float*)d_out;

    const size_t l1_elems = (size_t)NROWS * H;     // 25.2 MB bf16
    const size_t wp_elems = (size_t)H * KEXP;      // 10.6 MB bf16
    unsigned short* l1 = (unsigned short*)d_ws;
    unsigned short* wp = l1 + l1_elems;
    unsigned short* F  = wp + wp_elems;            // 226.5 MB bf16

    prep_expand<<<6144 + H, 256, 0, stream>>>(hidden, bw1, sw1, sc1, wp, F);
    kan1_gemm<<<256, 512, 0, stream>>>(F, wp, l1);
    kan2_kernel<<<NROWS / 4, 256, 0, stream>>>(l1, bw2, sw2, sc2, out);
}

// Round 8
// 324.595 us; speedup vs baseline: 1.2543x; 1.0245x over previous
//
#include <hip/hip_runtime.h>
#include <math.h>

// Problem constants
#define NROWS 16384   // 32*512
#define H     768
#define KEXP  6912    // 768 (silu*base_w) + 768*8 (bases*spline_w*scaler)
#define NCHUNK 108    // KEXP/64 K-steps
#define NITER 54      // 2 K-steps per iteration

typedef __attribute__((ext_vector_type(8))) short  bhalf8;
typedef __attribute__((ext_vector_type(4))) float  floatx4;

__device__ __forceinline__ unsigned short f2bf(float f) {
    unsigned int u = __float_as_uint(f);
    u = (u + 0x7FFFu + ((u >> 16) & 1u)) >> 16;   // RNE
    return (unsigned short)u;
}
__device__ __forceinline__ float bf2f(unsigned short h) {
    return __uint_as_float(((unsigned int)h) << 16);
}
__device__ __forceinline__ unsigned int pack2(unsigned short a, unsigned short b) {
    return (unsigned int)a | ((unsigned int)b << 16);
}
__device__ __forceinline__ float silu_f(float x) { return x / (1.0f + __expf(-x)); }

// Branch-free tanh-form GELU (|err vs exact erf-GELU| < ~1e-3 in u)
__device__ __forceinline__ float gelu_fast(float x) {
    float x3 = x * x * x;
    float y = fmaf(x3, 0.0356774081f, x * 0.7978845608f);
    float e = __expf(2.0f * y);
    float th = 1.0f - 2.0f / (e + 1.0f);
    return 0.5f * x * (1.0f + th);
}

// Closed-form cubic B-spline bases on uniform knots g[j] = (j-3)*0.4 - 1.
__device__ __forceinline__ void kan_bases(float x, float* __restrict__ b) {
    const float c6 = 0.166666666667f;
    float u  = fmaf(x, 2.5f, 5.5f);
    float fj = floorf(u);
    float t  = u - fj;
    int  j0  = (int)fj;
    float t2 = t * t, t3 = t2 * t;
    float n0 = t3 * c6;
    float n1 = fmaf(t3, -0.5f, fmaf(t2, 0.5f, fmaf(t, 0.5f, c6)));
    float n2 = fmaf(t3, 0.5f, fmaf(t2, -1.0f, 0.666666666667f));
    float omt = 1.0f - t;
    float n3 = omt * omt * omt * c6;
#pragma unroll
    for (int c = 0; c < 8; ++c) {
        int d = j0 - c;
        float v = (d == 0) ? n0 : 0.0f;
        v = (d == 1) ? n1 : v;
        v = (d == 2) ? n2 : v;
        v = (d == 3) ? n3 : v;
        b[c] = v;
    }
}

// ---- prep_expand (flat, scalar — ROUND-5/7 MEASURED-BEST, byte-identical):
//      blocks 0..6143 expand F (2048 elems/block, 8 STRIDED elems/thread ->
//      every store lane-consecutive). Blocks 6144..6911: W' rows.
__global__ __launch_bounds__(256) void prep_expand(
    const float* __restrict__ x, const float* __restrict__ bw,
    const float* __restrict__ sw, const float* __restrict__ sc,
    unsigned short* __restrict__ wp, unsigned short* __restrict__ F)
{
    const int b = blockIdx.x, t = threadIdx.x;
    if (b < 6144) {
        const int e0 = b * 2048 + t;
#pragma unroll
        for (int j = 0; j < 8; ++j) {
            int e = e0 + j * 256;
            int n = e / 768;                      // magic-mul
            int i = e - n * 768;
            float xv = x[e];                      // x row-major (N,768): linear in e
            unsigned short* out = F + (size_t)n * KEXP;
            out[i] = f2bf(silu_f(xv));            // 2B store, lane-consecutive
            float bb[8];
            kan_bases(xv, bb);
            uint4 pk;
            pk.x = pack2(f2bf(bb[0]), f2bf(bb[1]));
            pk.y = pack2(f2bf(bb[2]), f2bf(bb[3]));
            pk.z = pack2(f2bf(bb[4]), f2bf(bb[5]));
            pk.w = pack2(f2bf(bb[6]), f2bf(bb[7]));
            *(uint4*)(out + H + (size_t)i * 8) = pk;  // 16B store, lane-consecutive
        }
    } else {
        const int n = b - 6144;
        const float* bwr = bw + (size_t)n * H;
        unsigned short* out = wp + (size_t)n * KEXP;
        if (t < 96) {
            const float4* xp = (const float4*)(bwr + t * 8);
            float4 v0 = xp[0], v1 = xp[1];
            uint4 pk;
            pk.x = pack2(f2bf(v0.x), f2bf(v0.y));
            pk.y = pack2(f2bf(v0.z), f2bf(v0.w));
            pk.z = pack2(f2bf(v1.x), f2bf(v1.y));
            pk.w = pack2(f2bf(v1.z), f2bf(v1.w));
            *(uint4*)(out + t * 8) = pk;
        }
#pragma unroll
        for (int p = 0; p < 3; ++p) {
            int i = t + p * 256;
            float s = sc[(size_t)n * H + i];
            const float4* swp = (const float4*)(sw + ((size_t)n * H + i) * 8);
            float4 w0 = swp[0], w1 = swp[1];
            uint4 pk;
            pk.x = pack2(f2bf(w0.x * s), f2bf(w0.y * s));
            pk.y = pack2(f2bf(w0.z * s), f2bf(w0.w * s));
            pk.z = pack2(f2bf(w1.x * s), f2bf(w1.y * s));
            pk.w = pack2(f2bf(w1.z * s), f2bf(w1.w * s));
            *(uint4*)(out + H + (size_t)i * 8) = pk;
        }
    }
}

// ==== Layer 1+2 fused: 256x192 GEMM (r2 schedule VERBATIM, r6-measured
// 152.6us K-loop) + kan2 relocated into the epilogue.
// Epilogue: acc (f32, pre-bf16) -> gelu -> silu/bases -> dot with the 49KB
// L1-resident layer-2 weights (3 col-sets preloaded, col depends only on qn)
// -> shfl-reduce over the 16-lane lm group -> atomicAdd (16 contributors per
// out[row][o]: 4 wc waves x 4 colT blocks). Deletes l1 write+read (50MB) and
// the kan2 dispatch. No barriers after the K-loop's final one.

#define AS1 __attribute__((address_space(1)))
#define AS3 __attribute__((address_space(3)))

#define DSR(D, A, O) asm volatile("ds_read_b128 %0, %1 offset:" #O : "=v"(D) : "v"(A) : "memory")
#define LDA0(O) do{ DSR(fA0[0],avA[0],O); DSR(fA0[1],avA[1],O); DSR(fA0[2],avA[2],O); DSR(fA0[3],avA[3],O); \
                    DSR(fA0[4],avA[4],O); DSR(fA0[5],avA[5],O); DSR(fA0[6],avA[6],O); DSR(fA0[7],avA[7],O); }while(0)
#define LDA1(O) do{ DSR(fA1[0],avA[0],O); DSR(fA1[1],avA[1],O); DSR(fA1[2],avA[2],O); DSR(fA1[3],avA[3],O); \
                    DSR(fA1[4],avA[4],O); DSR(fA1[5],avA[5],O); DSR(fA1[6],avA[6],O); DSR(fA1[7],avA[7],O); }while(0)
#define LDB(O)  do{ DSR(fB[0],avB[0],O); DSR(fB[1],avB[1],O); }while(0)

#define MM0(QN) do{ \
    _Pragma("unroll") \
    for (int kk = 0; kk < 2; ++kk) \
        _Pragma("unroll") \
        for (int im = 0; im < 4; ++im) \
            acc0[QN][im] = __builtin_amdgcn_mfma_f32_16x16x32_bf16( \
                fA0[im*2+kk], fB[kk], acc0[QN][im], 0, 0, 0); \
}while(0)
#define MM1(QN) do{ \
    _Pragma("unroll") \
    for (int kk = 0; kk < 2; ++kk) \
        _Pragma("unroll") \
        for (int im = 0; im < 4; ++im) \
            acc1[QN][im] = __builtin_amdgcn_mfma_f32_16x16x32_bf16( \
                fA1[im*2+kk], fB[kk], acc1[QN][im], 0, 0, 0); \
}while(0)

#define STG_A(BF,HH,KS) do{ \
    __builtin_amdgcn_global_load_lds((const AS1 void*)(pA##HH[0] + (size_t)(KS)*64), \
        (AS3 void*)&sA[BF][HH][wb8], 16, 0, 0); \
    __builtin_amdgcn_global_load_lds((const AS1 void*)(pA##HH[1] + (size_t)(KS)*64), \
        (AS3 void*)&sA[BF][HH][4096 + wb8], 16, 0, 0); \
}while(0)
#define STG_B(BF,QN,KS) \
    __builtin_amdgcn_global_load_lds((const AS1 void*)(pB[QN] + (size_t)(KS)*64), \
        (AS3 void*)&sB[BF][QN][wb8], 16, 0, 0)

#define PH_MID do{ __builtin_amdgcn_s_barrier(); \
    asm volatile("s_waitcnt lgkmcnt(0)" ::: "memory"); \
    __builtin_amdgcn_sched_barrier(0); \
    __builtin_amdgcn_s_setprio(1); }while(0)
#define PH_END do{ __builtin_amdgcn_s_setprio(0); \
    __builtin_amdgcn_sched_barrier(0); \
    __builtin_amdgcn_s_barrier(); }while(0)
#define PH_END_VMN(N) do{ __builtin_amdgcn_s_setprio(0); \
    __builtin_amdgcn_sched_barrier(0); \
    asm volatile("s_waitcnt vmcnt(" #N ")" ::: "memory"); \
    __builtin_amdgcn_s_barrier(); }while(0)

// Fused layer-2 epilogue for one qm-half (ACC = acc0 or acc1, QMOFF = 0 or 128).
// All indices compile-time after unroll (rule #20 safe).
#define EPI_HALF(ACC, QMOFF) do{ \
    _Pragma("unroll") \
    for (int im = 0; im < 4; ++im) { \
        _Pragma("unroll") \
        for (int rg = 0; rg < 4; ++rg) { \
            float p0 = 0.f, p1 = 0.f; \
            _Pragma("unroll") \
            for (int qn = 0; qn < 3; ++qn) { \
                float v = ACC[qn][im][rg]; \
                float u = gelu_fast(v); \
                float f0v = silu_f(u); \
                float bb[8]; \
                kan_bases(u, bb); \
                float t0 = bb[0]*wsw[qn][0][0].x + bb[1]*wsw[qn][0][0].y \
                         + bb[2]*wsw[qn][0][0].z + bb[3]*wsw[qn][0][0].w \
                         + bb[4]*wsw[qn][0][1].x + bb[5]*wsw[qn][0][1].y \
                         + bb[6]*wsw[qn][0][1].z + bb[7]*wsw[qn][0][1].w; \
                float t1 = bb[0]*wsw[qn][1][0].x + bb[1]*wsw[qn][1][0].y \
                         + bb[2]*wsw[qn][1][0].z + bb[3]*wsw[qn][1][0].w \
                         + bb[4]*wsw[qn][1][1].x + bb[5]*wsw[qn][1][1].y \
                         + bb[6]*wsw[qn][1][1].z + bb[7]*wsw[qn][1][1].w; \
                p0 += fmaf(f0v, wbw[qn][0], wsc[qn][0] * t0); \
                p1 += fmaf(f0v, wbw[qn][1], wsc[qn][1] * t1); \
            } \
            _Pragma("unroll") \
            for (int off = 8; off > 0; off >>= 1) { \
                p0 += __shfl_xor(p0, off, 64); \
                p1 += __shfl_xor(p1, off, 64); \
            } \
            if (lm == 0) { \
                int row = rowBase + (QMOFF) + wr*64 + im*16 + quad*4 + rg; \
                atomicAdd(&outp[(size_t)row * 2 + 0], p0); \
                atomicAdd(&outp[(size_t)row * 2 + 1], p1); \
            } \
        } \
    } \
}while(0)

__global__ __launch_bounds__(512, 2) void kan1_fused(
    const unsigned short* __restrict__ F, const unsigned short* __restrict__ wp,
    const float* __restrict__ bw2, const float* __restrict__ sw2,
    const float* __restrict__ sc2, float* __restrict__ outp)
{
    __shared__ __align__(16) unsigned short sA[2][2][8192];  // [buf][half 128rows][128*64]
    __shared__ __align__(16) unsigned short sB[2][3][4096];  // [buf][third 64rows][64*64]

    const int b = blockIdx.x;                  // 0..255
    const int s = b >> 3;
    const int rowT = (b & 7) * 8 + (s >> 2);   // 0..63
    const int colT = s & 3;                    // 0..3
    const int rowBase = rowT * 256, colBase = colT * 192;

    const int t = threadIdx.x;
    const int lane = t & 63;
    const int quad = lane >> 4, lm = lane & 15, p7 = lane & 7;
    const int wv = t >> 6, wr = wv & 1, wc = wv >> 1;   // 2M x 4N wave grid

    const int rr = t >> 3;                    // 0..63
    const int slotx = (t & 7) ^ (rr & 7);
    const int wb8 = (t & 448) * 8;            // wave-uniform LDS elem base (wv*512)

    const unsigned short* pA0[2]; const unsigned short* pA1[2];
    const unsigned short* pB[3];
#pragma unroll
    for (int p = 0; p < 2; ++p) {
        pA0[p] = F + (size_t)(rowBase +       p*64 + rr) * KEXP + slotx*8;
        pA1[p] = F + (size_t)(rowBase + 128 + p*64 + rr) * KEXP + slotx*8;
    }
#pragma unroll
    for (int q = 0; q < 3; ++q)
        pB[q] = wp + (size_t)(colBase + q*64 + rr) * KEXP + slotx*8;

    unsigned int avA[8], avB[2];
    {
        unsigned int aB = (unsigned int)(size_t)(AS3 unsigned short*)&sA[0][0][0];
        unsigned int bB = (unsigned int)(size_t)(AS3 unsigned short*)&sB[0][0][0];
#pragma unroll
        for (int im = 0; im < 4; ++im)
#pragma unroll
            for (int kk = 0; kk < 2; ++kk)
                avA[im*2+kk] = aB + (unsigned)(((wr*64 + im*16 + lm)*64 + (((kk*4+quad)^p7)*8)) * 2);
#pragma unroll
        for (int kk = 0; kk < 2; ++kk)
            avB[kk] = bB + (unsigned)(((wc*16 + lm)*64 + (((kk*4+quad)^p7)*8)) * 2);
    }

    floatx4 acc0[3][4] = {};   // [qn][im], qm=0 rows
    floatx4 acc1[3][4] = {};   // qm=1 rows
    bhalf8 fA0[8], fA1[8], fB[2];

    // prologue: buf0 <- ks0 (7 loads), buf1 <- ks1 minus B2 (6 loads); retire 5
    STG_A(0,0,0); STG_A(0,1,0); STG_B(0,0,0); STG_B(0,1,0); STG_B(0,2,0);
    STG_A(1,0,1); STG_A(1,1,1); STG_B(1,0,1); STG_B(1,1,1);
    asm volatile("s_waitcnt vmcnt(8)" ::: "memory");
    __builtin_amdgcn_s_barrier();

#pragma unroll 1
    for (int i = 0; i < NITER; ++i) {
        const int k1 = 2*i + 1;
        const int k2 = (2*i + 2 > 107) ? 107 : 2*i + 2;
        const int k3 = (2*i + 3 > 107) ? 107 : 2*i + 3;
        // K-step 2i from buf0
        LDA0(0);     LDB(0);     STG_B(1,2,k1);               PH_MID; MM0(0);         PH_END_VMN(10);
        LDA1(16384);             STG_A(0,0,k2);               PH_MID; MM1(0);         PH_END_VMN(10);
        LDB(8192);               STG_A(0,1,k2);               PH_MID; MM1(1); MM0(1); PH_END_VMN(11);
        LDB(16384);              STG_B(0,0,k2); STG_B(0,1,k2);PH_MID; MM0(2); MM1(2); PH_END_VMN(8);
        // K-step 2i+1 from buf1
        LDA0(32768); LDB(24576); STG_B(0,2,k2);               PH_MID; MM0(0);         PH_END;
        LDA1(49152);             STG_A(1,0,k3);               PH_MID; MM1(0);         PH_END_VMN(10);
        LDB(32768);              STG_A(1,1,k3);               PH_MID; MM1(1); MM0(1); PH_END_VMN(11);
        LDB(40960);              STG_B(1,0,k3); STG_B(1,1,k3);PH_MID; MM0(2); MM1(2); PH_END_VMN(8);
    }

    // ---- fused layer-2 epilogue ----
    // preload this thread's 3 column weight sets (col = colBase+qn*64+wc*16+lm)
    float  wbw[3][2], wsc[3][2];
    float4 wsw[3][2][2];
#pragma unroll
    for (int qn = 0; qn < 3; ++qn) {
        const int i = colBase + qn*64 + wc*16 + lm;
        wbw[qn][0] = bw2[i];      wbw[qn][1] = bw2[H + i];
        wsc[qn][0] = sc2[i];      wsc[qn][1] = sc2[H + i];
        const float4* q0 = (const float4*)(sw2 + (size_t)i * 8);
        const float4* q1 = (const float4*)(sw2 + (size_t)(H + i) * 8);
        wsw[qn][0][0] = q0[0];    wsw[qn][0][1] = q0[1];
        wsw[qn][1][0] = q1[0];    wsw[qn][1][1] = q1[1];
    }
    EPI_HALF(acc0, 0);
    EPI_HALF(acc1, 128);
}

extern "C" void kernel_launch(void* const* d_in, const int* in_sizes, int n_in,
                              void* d_out, int out_size, void* d_ws, size_t ws_size,
                              hipStream_t stream) {
    const float* hidden = (const float*)d_in[0];
    const float* bw1    = (const float*)d_in[1];
    const float* sw1    = (const float*)d_in[2];
    const float* sc1    = (const float*)d_in[3];
    const float* bw2    = (const float*)d_in[4];
    const float* sw2    = (const float*)d_in[5];
    const float* sc2    = (const float*)d_in[6];
    float* out = (float*)d_out;

    const size_t wp_elems = (size_t)H * KEXP;      // 10.6 MB bf16
    unsigned short* wp = (unsigned short*)d_ws;
    unsigned short* F  = wp + wp_elems;            // 226.5 MB bf16

    hipMemsetAsync(d_out, 0, (size_t)out_size, stream);   // graph-capturable
    prep_expand<<<6144 + H, 256, 0, stream>>>(hidden, bw1, sw1, sc1, wp, F);
    kan1_fused<<<256, 512, 0, stream>>>(F, wp, bw2, sw2, sc2, out);
}

// Round 9
// 308.197 us; speedup vs baseline: 1.3210x; 1.0532x over previous
//
#include <hip/hip_runtime.h>
#include <math.h>

// Problem constants
#define NROWS 16384   // 32*512
#define H     768
#define KEXP  6912    // 768 (silu*base_w) + 768*8 (bases*spline_w*scaler)
#define NCHUNK 108    // KEXP/64 K-steps
#define NITER 54      // 2 K-steps per iteration

typedef __attribute__((ext_vector_type(8))) short  bhalf8;
typedef __attribute__((ext_vector_type(4))) float  floatx4;
typedef __attribute__((ext_vector_type(4))) unsigned int uintx4;

__device__ __forceinline__ unsigned short f2bf(float f) {
    unsigned int u = __float_as_uint(f);
    u = (u + 0x7FFFu + ((u >> 16) & 1u)) >> 16;   // RNE
    return (unsigned short)u;
}
__device__ __forceinline__ float bf2f(unsigned short h) {
    return __uint_as_float(((unsigned int)h) << 16);
}
__device__ __forceinline__ unsigned int pack2(unsigned short a, unsigned short b) {
    return (unsigned int)a | ((unsigned int)b << 16);
}
// silu via fast rcp (v_rcp_f32 ~1e-7 rel err; output budget 0.42, current 0.125)
__device__ __forceinline__ float silu_f(float x) {
    return x * __builtin_amdgcn_rcpf(1.0f + __expf(-x));
}

// Branch-free tanh-form GELU (|err vs exact erf-GELU| < ~1e-3 in u), fast rcp
__device__ __forceinline__ float gelu_fast(float x) {
    float x3 = x * x * x;
    float y = fmaf(x3, 0.0356774081f, x * 0.7978845608f);
    float e = __expf(2.0f * y);
    float th = 1.0f - 2.0f * __builtin_amdgcn_rcpf(e + 1.0f);
    return 0.5f * x * (1.0f + th);
}

// Closed-form cubic B-spline bases on uniform knots g[j] = (j-3)*0.4 - 1.
__device__ __forceinline__ void kan_bases(float x, float* __restrict__ b) {
    const float c6 = 0.166666666667f;
    float u  = fmaf(x, 2.5f, 5.5f);
    float fj = floorf(u);
    float t  = u - fj;
    int  j0  = (int)fj;
    float t2 = t * t, t3 = t2 * t;
    float n0 = t3 * c6;
    float n1 = fmaf(t3, -0.5f, fmaf(t2, 0.5f, fmaf(t, 0.5f, c6)));
    float n2 = fmaf(t3, 0.5f, fmaf(t2, -1.0f, 0.666666666667f));
    float omt = 1.0f - t;
    float n3 = omt * omt * omt * c6;
#pragma unroll
    for (int c = 0; c < 8; ++c) {
        int d = j0 - c;
        float v = (d == 0) ? n0 : 0.0f;
        v = (d == 1) ? n1 : v;
        v = (d == 2) ? n2 : v;
        v = (d == 3) ? n3 : v;
        b[c] = v;
    }
}

// ---- prep_expand (flat, scalar — r5/r7 measured-best structure) with
//      NONTEMPORAL stores: F (237MB) is streaming-write, L2 can't hold it;
//      nt bypasses write-allocate. Diagnostic: if prep time unchanged, prep
//      is at pure HBM-write roofline.
__global__ __launch_bounds__(256) void prep_expand(
    const float* __restrict__ x, const float* __restrict__ bw,
    const float* __restrict__ sw, const float* __restrict__ sc,
    unsigned short* __restrict__ wp, unsigned short* __restrict__ F)
{
    const int b = blockIdx.x, t = threadIdx.x;
    if (b < 6144) {
        const int e0 = b * 2048 + t;
#pragma unroll
        for (int j = 0; j < 8; ++j) {
            int e = e0 + j * 256;
            int n = e / 768;                      // magic-mul
            int i = e - n * 768;
            float xv = x[e];                      // x row-major (N,768): linear in e
            unsigned short* out = F + (size_t)n * KEXP;
            __builtin_nontemporal_store(f2bf(silu_f(xv)), out + i);   // 2B, lane-consec
            float bb[8];
            kan_bases(xv, bb);
            uintx4 pk;
            pk.x = pack2(f2bf(bb[0]), f2bf(bb[1]));
            pk.y = pack2(f2bf(bb[2]), f2bf(bb[3]));
            pk.z = pack2(f2bf(bb[4]), f2bf(bb[5]));
            pk.w = pack2(f2bf(bb[6]), f2bf(bb[7]));
            __builtin_nontemporal_store(pk, (uintx4*)(out + H + (size_t)i * 8)); // 16B
        }
    } else {
        const int n = b - 6144;
        const float* bwr = bw + (size_t)n * H;
        unsigned short* out = wp + (size_t)n * KEXP;
        if (t < 96) {
            const float4* xp = (const float4*)(bwr + t * 8);
            float4 v0 = xp[0], v1 = xp[1];
            uintx4 pk;
            pk.x = pack2(f2bf(v0.x), f2bf(v0.y));
            pk.y = pack2(f2bf(v0.z), f2bf(v0.w));
            pk.z = pack2(f2bf(v1.x), f2bf(v1.y));
            pk.w = pack2(f2bf(v1.z), f2bf(v1.w));
            __builtin_nontemporal_store(pk, (uintx4*)(out + t * 8));
        }
#pragma unroll
        for (int p = 0; p < 3; ++p) {
            int i = t + p * 256;
            float s = sc[(size_t)n * H + i];
            const float4* swp = (const float4*)(sw + ((size_t)n * H + i) * 8);
            float4 w0 = swp[0], w1 = swp[1];
            uintx4 pk;
            pk.x = pack2(f2bf(w0.x * s), f2bf(w0.y * s));
            pk.y = pack2(f2bf(w0.z * s), f2bf(w0.w * s));
            pk.z = pack2(f2bf(w1.x * s), f2bf(w1.y * s));
            pk.w = pack2(f2bf(w1.z * s), f2bf(w1.w * s));
            __builtin_nontemporal_store(pk, (uintx4*)(out + H + (size_t)i * 8));
        }
    }
}

// ==== Layer 1+2 fused: 256x192 GEMM (r2 K-loop VERBATIM) + qn-outer epilogue.
// r8 lesson: per-element weight indexing made the compiler rematerialize ~400
// VMEM loads/thread in the epilogue (VGPR pinned at 108; +51us VALU/issue).
// LDS=114.7KB => 1 block/CU => VGPR growth is FREE up to 256. qn-outer loads
// each weight set ONCE (24 loads/thread), accumulates into p[4][4] partials.

#define AS1 __attribute__((address_space(1)))
#define AS3 __attribute__((address_space(3)))

#define DSR(D, A, O) asm volatile("ds_read_b128 %0, %1 offset:" #O : "=v"(D) : "v"(A) : "memory")
#define LDA0(O) do{ DSR(fA0[0],avA[0],O); DSR(fA0[1],avA[1],O); DSR(fA0[2],avA[2],O); DSR(fA0[3],avA[3],O); \
                    DSR(fA0[4],avA[4],O); DSR(fA0[5],avA[5],O); DSR(fA0[6],avA[6],O); DSR(fA0[7],avA[7],O); }while(0)
#define LDA1(O) do{ DSR(fA1[0],avA[0],O); DSR(fA1[1],avA[1],O); DSR(fA1[2],avA[2],O); DSR(fA1[3],avA[3],O); \
                    DSR(fA1[4],avA[4],O); DSR(fA1[5],avA[5],O); DSR(fA1[6],avA[6],O); DSR(fA1[7],avA[7],O); }while(0)
#define LDB(O)  do{ DSR(fB[0],avB[0],O); DSR(fB[1],avB[1],O); }while(0)

#define MM0(QN) do{ \
    _Pragma("unroll") \
    for (int kk = 0; kk < 2; ++kk) \
        _Pragma("unroll") \
        for (int im = 0; im < 4; ++im) \
            acc0[QN][im] = __builtin_amdgcn_mfma_f32_16x16x32_bf16( \
                fA0[im*2+kk], fB[kk], acc0[QN][im], 0, 0, 0); \
}while(0)
#define MM1(QN) do{ \
    _Pragma("unroll") \
    for (int kk = 0; kk < 2; ++kk) \
        _Pragma("unroll") \
        for (int im = 0; im < 4; ++im) \
            acc1[QN][im] = __builtin_amdgcn_mfma_f32_16x16x32_bf16( \
                fA1[im*2+kk], fB[kk], acc1[QN][im], 0, 0, 0); \
}while(0)

#define STG_A(BF,HH,KS) do{ \
    __builtin_amdgcn_global_load_lds((const AS1 void*)(pA##HH[0] + (size_t)(KS)*64), \
        (AS3 void*)&sA[BF][HH][wb8], 16, 0, 0); \
    __builtin_amdgcn_global_load_lds((const AS1 void*)(pA##HH[1] + (size_t)(KS)*64), \
        (AS3 void*)&sA[BF][HH][4096 + wb8], 16, 0, 0); \
}while(0)
#define STG_B(BF,QN,KS) \
    __builtin_amdgcn_global_load_lds((const AS1 void*)(pB[QN] + (size_t)(KS)*64), \
        (AS3 void*)&sB[BF][QN][wb8], 16, 0, 0)

#define PH_MID do{ __builtin_amdgcn_s_barrier(); \
    asm volatile("s_waitcnt lgkmcnt(0)" ::: "memory"); \
    __builtin_amdgcn_sched_barrier(0); \
    __builtin_amdgcn_s_setprio(1); }while(0)
#define PH_END do{ __builtin_amdgcn_s_setprio(0); \
    __builtin_amdgcn_sched_barrier(0); \
    __builtin_amdgcn_s_barrier(); }while(0)
#define PH_END_VMN(N) do{ __builtin_amdgcn_s_setprio(0); \
    __builtin_amdgcn_sched_barrier(0); \
    asm volatile("s_waitcnt vmcnt(" #N ")" ::: "memory"); \
    __builtin_amdgcn_s_barrier(); }while(0)

__global__ __launch_bounds__(512, 2) void kan1_fused(
    const unsigned short* __restrict__ F, const unsigned short* __restrict__ wp,
    const float* __restrict__ bw2, const float* __restrict__ sw2,
    const float* __restrict__ sc2, float* __restrict__ outp)
{
    __shared__ __align__(16) unsigned short sA[2][2][8192];  // [buf][half 128rows][128*64]
    __shared__ __align__(16) unsigned short sB[2][3][4096];  // [buf][third 64rows][64*64]

    const int b = blockIdx.x;                  // 0..255
    const int s = b >> 3;
    const int rowT = (b & 7) * 8 + (s >> 2);   // 0..63
    const int colT = s & 3;                    // 0..3
    const int rowBase = rowT * 256, colBase = colT * 192;

    const int t = threadIdx.x;
    const int lane = t & 63;
    const int quad = lane >> 4, lm = lane & 15, p7 = lane & 7;
    const int wv = t >> 6, wr = wv & 1, wc = wv >> 1;   // 2M x 4N wave grid

    const int rr = t >> 3;                    // 0..63
    const int slotx = (t & 7) ^ (rr & 7);
    const int wb8 = (t & 448) * 8;            // wave-uniform LDS elem base (wv*512)

    const unsigned short* pA0[2]; const unsigned short* pA1[2];
    const unsigned short* pB[3];
#pragma unroll
    for (int p = 0; p < 2; ++p) {
        pA0[p] = F + (size_t)(rowBase +       p*64 + rr) * KEXP + slotx*8;
        pA1[p] = F + (size_t)(rowBase + 128 + p*64 + rr) * KEXP + slotx*8;
    }
#pragma unroll
    for (int q = 0; q < 3; ++q)
        pB[q] = wp + (size_t)(colBase + q*64 + rr) * KEXP + slotx*8;

    unsigned int avA[8], avB[2];
    {
        unsigned int aB = (unsigned int)(size_t)(AS3 unsigned short*)&sA[0][0][0];
        unsigned int bB = (unsigned int)(size_t)(AS3 unsigned short*)&sB[0][0][0];
#pragma unroll
        for (int im = 0; im < 4; ++im)
#pragma unroll
            for (int kk = 0; kk < 2; ++kk)
                avA[im*2+kk] = aB + (unsigned)(((wr*64 + im*16 + lm)*64 + (((kk*4+quad)^p7)*8)) * 2);
#pragma unroll
        for (int kk = 0; kk < 2; ++kk)
            avB[kk] = bB + (unsigned)(((wc*16 + lm)*64 + (((kk*4+quad)^p7)*8)) * 2);
    }

    floatx4 acc0[3][4] = {};   // [qn][im], qm=0 rows
    floatx4 acc1[3][4] = {};   // qm=1 rows
    bhalf8 fA0[8], fA1[8], fB[2];

    // prologue: buf0 <- ks0 (7 loads), buf1 <- ks1 minus B2 (6 loads); retire 5
    STG_A(0,0,0); STG_A(0,1,0); STG_B(0,0,0); STG_B(0,1,0); STG_B(0,2,0);
    STG_A(1,0,1); STG_A(1,1,1); STG_B(1,0,1); STG_B(1,1,1);
    asm volatile("s_waitcnt vmcnt(8)" ::: "memory");
    __builtin_amdgcn_s_barrier();

#pragma unroll 1
    for (int i = 0; i < NITER; ++i) {
        const int k1 = 2*i + 1;
        const int k2 = (2*i + 2 > 107) ? 107 : 2*i + 2;
        const int k3 = (2*i + 3 > 107) ? 107 : 2*i + 3;
        // K-step 2i from buf0
        LDA0(0);     LDB(0);     STG_B(1,2,k1);               PH_MID; MM0(0);         PH_END_VMN(10);
        LDA1(16384);             STG_A(0,0,k2);               PH_MID; MM1(0);         PH_END_VMN(10);
        LDB(8192);               STG_A(0,1,k2);               PH_MID; MM1(1); MM0(1); PH_END_VMN(11);
        LDB(16384);              STG_B(0,0,k2); STG_B(0,1,k2);PH_MID; MM0(2); MM1(2); PH_END_VMN(8);
        // K-step 2i+1 from buf1
        LDA0(32768); LDB(24576); STG_B(0,2,k2);               PH_MID; MM0(0);         PH_END;
        LDA1(49152);             STG_A(1,0,k3);               PH_MID; MM1(0);         PH_END_VMN(10);
        LDB(32768);              STG_A(1,1,k3);               PH_MID; MM1(1); MM0(1); PH_END_VMN(11);
        LDB(40960);              STG_B(1,0,k3); STG_B(1,1,k3);PH_MID; MM0(2); MM1(2); PH_END_VMN(8);
    }

    // ---- fused layer-2 epilogue, qn-OUTER: each weight set loaded once ----
    float p00[4][4] = {}, p01[4][4] = {};   // half0 (qm=0) partials, outputs 0/1
    float p10[4][4] = {}, p11[4][4] = {};   // half1 (qm=1)
#pragma unroll
    for (int qn = 0; qn < 3; ++qn) {
        const int i = colBase + qn*64 + wc*16 + lm;
        const float bwa = bw2[i], bwb = bw2[H + i];
        const float sca = sc2[i], scb = sc2[H + i];
        const float4* q0 = (const float4*)(sw2 + (size_t)i * 8);
        const float4* q1 = (const float4*)(sw2 + (size_t)(H + i) * 8);
        const float4 wa0 = q0[0], wa1 = q0[1];
        const float4 wb0 = q1[0], wb1 = q1[1];
#pragma unroll
        for (int im = 0; im < 4; ++im)
#pragma unroll
        for (int rg = 0; rg < 4; ++rg) {
            {
                float u = gelu_fast(acc0[qn][im][rg]);
                float f0v = silu_f(u);
                float bb[8];
                kan_bases(u, bb);
                float t0 = bb[0]*wa0.x + bb[1]*wa0.y + bb[2]*wa0.z + bb[3]*wa0.w
                         + bb[4]*wa1.x + bb[5]*wa1.y + bb[6]*wa1.z + bb[7]*wa1.w;
                float t1 = bb[0]*wb0.x + bb[1]*wb0.y + bb[2]*wb0.z + bb[3]*wb0.w
                         + bb[4]*wb1.x + bb[5]*wb1.y + bb[6]*wb1.z + bb[7]*wb1.w;
                p00[im][rg] += fmaf(f0v, bwa, sca * t0);
                p01[im][rg] += fmaf(f0v, bwb, scb * t1);
            }
            {
                float u = gelu_fast(acc1[qn][im][rg]);
                float f0v = silu_f(u);
                float bb[8];
                kan_bases(u, bb);
                float t0 = bb[0]*wa0.x + bb[1]*wa0.y + bb[2]*wa0.z + bb[3]*wa0.w
                         + bb[4]*wa1.x + bb[5]*wa1.y + bb[6]*wa1.z + bb[7]*wa1.w;
                float t1 = bb[0]*wb0.x + bb[1]*wb0.y + bb[2]*wb0.z + bb[3]*wb0.w
                         + bb[4]*wb1.x + bb[5]*wb1.y + bb[6]*wb1.z + bb[7]*wb1.w;
                p10[im][rg] += fmaf(f0v, bwa, sca * t0);
                p11[im][rg] += fmaf(f0v, bwb, scb * t1);
            }
        }
    }
    // reduce over the 16-lane lm group; 16 contributors/output (4 wc x 4 colT)
#pragma unroll
    for (int im = 0; im < 4; ++im)
#pragma unroll
    for (int rg = 0; rg < 4; ++rg) {
        float a0 = p00[im][rg], a1 = p01[im][rg];
        float c0 = p10[im][rg], c1 = p11[im][rg];
#pragma unroll
        for (int off = 8; off > 0; off >>= 1) {
            a0 += __shfl_xor(a0, off, 64);
            a1 += __shfl_xor(a1, off, 64);
            c0 += __shfl_xor(c0, off, 64);
            c1 += __shfl_xor(c1, off, 64);
        }
        if (lm == 0) {
            const int row0 = rowBase + wr*64 + im*16 + quad*4 + rg;
            atomicAdd(&outp[(size_t)row0 * 2 + 0], a0);
            atomicAdd(&outp[(size_t)row0 * 2 + 1], a1);
            const int row1 = row0 + 128;
            atomicAdd(&outp[(size_t)row1 * 2 + 0], c0);
            atomicAdd(&outp[(size_t)row1 * 2 + 1], c1);
        }
    }
}

extern "C" void kernel_launch(void* const* d_in, const int* in_sizes, int n_in,
                              void* d_out, int out_size, void* d_ws, size_t ws_size,
                              hipStream_t stream) {
    const float* hidden = (const float*)d_in[0];
    const float* bw1    = (const float*)d_in[1];
    const float* sw1    = (const float*)d_in[2];
    const float* sc1    = (const float*)d_in[3];
    const float* bw2    = (const float*)d_in[4];
    const float* sw2    = (const float*)d_in[5];
    const float* sc2    = (const float*)d_in[6];
    float* out = (float*)d_out;

    const size_t wp_elems = (size_t)H * KEXP;      // 10.6 MB bf16
    unsigned short* wp = (unsigned short*)d_ws;
    unsigned short* F  = wp + wp_elems;            // 226.5 MB bf16

    hipMemsetAsync(d_out, 0, (size_t)out_size, stream);   // graph-capturable
    prep_expand<<<6144 + H, 256, 0, stream>>>(hidden, bw1, sw1, sc1, wp, F);
    kan1_fused<<<256, 512, 0, stream>>>(F, wp, bw2, sw2, sc2, out);
}

// Round 10
// 307.781 us; speedup vs baseline: 1.3228x; 1.0014x over previous
//
#include <hip/hip_runtime.h>
#include <math.h>

// Problem constants
#define NROWS 16384   // 32*512
#define H     768
#define KEXP  6912    // 768 (silu*base_w) + 768*8 (bases*spline_w*scaler)
#define NCHUNK 108    // KEXP/64 K-steps
#define NITER 54      // 2 K-steps per iteration

typedef __attribute__((ext_vector_type(8))) short  bhalf8;
typedef __attribute__((ext_vector_type(4))) float  floatx4;
typedef __attribute__((ext_vector_type(4))) unsigned int uintx4;

__device__ __forceinline__ unsigned short f2bf(float f) {
    unsigned int u = __float_as_uint(f);
    u = (u + 0x7FFFu + ((u >> 16) & 1u)) >> 16;   // RNE
    return (unsigned short)u;
}
__device__ __forceinline__ float bf2f(unsigned short h) {
    return __uint_as_float(((unsigned int)h) << 16);
}
__device__ __forceinline__ unsigned int pack2(unsigned short a, unsigned short b) {
    return (unsigned int)a | ((unsigned int)b << 16);
}
// silu via fast rcp (v_rcp_f32 ~1e-7 rel err)
__device__ __forceinline__ float silu_f(float x) {
    return x * __builtin_amdgcn_rcpf(1.0f + __expf(-x));
}

// Branch-free tanh-form GELU (|err vs exact erf-GELU| < ~1e-3 in u), fast rcp
__device__ __forceinline__ float gelu_fast(float x) {
    float x3 = x * x * x;
    float y = fmaf(x3, 0.0356774081f, x * 0.7978845608f);
    float e = __expf(2.0f * y);
    float th = 1.0f - 2.0f * __builtin_amdgcn_rcpf(e + 1.0f);
    return 0.5f * x * (1.0f + th);
}

// Closed-form cubic B-spline bases on uniform knots g[j] = (j-3)*0.4 - 1.
__device__ __forceinline__ void kan_bases(float x, float* __restrict__ b) {
    const float c6 = 0.166666666667f;
    float u  = fmaf(x, 2.5f, 5.5f);
    float fj = floorf(u);
    float t  = u - fj;
    int  j0  = (int)fj;
    float t2 = t * t, t3 = t2 * t;
    float n0 = t3 * c6;
    float n1 = fmaf(t3, -0.5f, fmaf(t2, 0.5f, fmaf(t, 0.5f, c6)));
    float n2 = fmaf(t3, 0.5f, fmaf(t2, -1.0f, 0.666666666667f));
    float omt = 1.0f - t;
    float n3 = omt * omt * omt * c6;
#pragma unroll
    for (int c = 0; c < 8; ++c) {
        int d = j0 - c;
        float v = (d == 0) ? n0 : 0.0f;
        v = (d == 1) ? n1 : v;
        v = (d == 2) ? n2 : v;
        v = (d == 3) ? n3 : v;
        b[c] = v;
    }
}

// ---- prep_expand: r9 version byte-identical (flat scalar, nt stores).
__global__ __launch_bounds__(256) void prep_expand(
    const float* __restrict__ x, const float* __restrict__ bw,
    const float* __restrict__ sw, const float* __restrict__ sc,
    unsigned short* __restrict__ wp, unsigned short* __restrict__ F)
{
    const int b = blockIdx.x, t = threadIdx.x;
    if (b < 6144) {
        const int e0 = b * 2048 + t;
#pragma unroll
        for (int j = 0; j < 8; ++j) {
            int e = e0 + j * 256;
            int n = e / 768;                      // magic-mul
            int i = e - n * 768;
            float xv = x[e];                      // x row-major (N,768): linear in e
            unsigned short* out = F + (size_t)n * KEXP;
            __builtin_nontemporal_store(f2bf(silu_f(xv)), out + i);   // 2B, lane-consec
            float bb[8];
            kan_bases(xv, bb);
            uintx4 pk;
            pk.x = pack2(f2bf(bb[0]), f2bf(bb[1]));
            pk.y = pack2(f2bf(bb[2]), f2bf(bb[3]));
            pk.z = pack2(f2bf(bb[4]), f2bf(bb[5]));
            pk.w = pack2(f2bf(bb[6]), f2bf(bb[7]));
            __builtin_nontemporal_store(pk, (uintx4*)(out + H + (size_t)i * 8)); // 16B
        }
    } else {
        const int n = b - 6144;
        const float* bwr = bw + (size_t)n * H;
        unsigned short* out = wp + (size_t)n * KEXP;
        if (t < 96) {
            const float4* xp = (const float4*)(bwr + t * 8);
            float4 v0 = xp[0], v1 = xp[1];
            uintx4 pk;
            pk.x = pack2(f2bf(v0.x), f2bf(v0.y));
            pk.y = pack2(f2bf(v0.z), f2bf(v0.w));
            pk.z = pack2(f2bf(v1.x), f2bf(v1.y));
            pk.w = pack2(f2bf(v1.z), f2bf(v1.w));
            __builtin_nontemporal_store(pk, (uintx4*)(out + t * 8));
        }
#pragma unroll
        for (int p = 0; p < 3; ++p) {
            int i = t + p * 256;
            float s = sc[(size_t)n * H + i];
            const float4* swp = (const float4*)(sw + ((size_t)n * H + i) * 8);
            float4 w0 = swp[0], w1 = swp[1];
            uintx4 pk;
            pk.x = pack2(f2bf(w0.x * s), f2bf(w0.y * s));
            pk.y = pack2(f2bf(w0.z * s), f2bf(w0.w * s));
            pk.z = pack2(f2bf(w1.x * s), f2bf(w1.y * s));
            pk.w = pack2(f2bf(w1.z * s), f2bf(w1.w * s));
            __builtin_nontemporal_store(pk, (uintx4*)(out + H + (size_t)i * 8));
        }
    }
}

// ==== Layer 1+2 fused: r2 K-loop VERBATIM + low-pressure epilogue.
// r9 lesson: qn-outer with both halves live = ~196 reg pressure; compiler
// stayed at 108 VGPR -> spill/remat, epilogue cost 37us vs ~9us intrinsic.
// Fix: per-HALF passes (peak ~150 regs) + __launch_bounds__(512,1) — LDS
// (114.7KB) already caps at 1 block/CU = 2 waves/SIMD, so the looser bound
// costs zero occupancy and un-caps the allocator.

#define AS1 __attribute__((address_space(1)))
#define AS3 __attribute__((address_space(3)))

#define DSR(D, A, O) asm volatile("ds_read_b128 %0, %1 offset:" #O : "=v"(D) : "v"(A) : "memory")
#define LDA0(O) do{ DSR(fA0[0],avA[0],O); DSR(fA0[1],avA[1],O); DSR(fA0[2],avA[2],O); DSR(fA0[3],avA[3],O); \
                    DSR(fA0[4],avA[4],O); DSR(fA0[5],avA[5],O); DSR(fA0[6],avA[6],O); DSR(fA0[7],avA[7],O); }while(0)
#define LDA1(O) do{ DSR(fA1[0],avA[0],O); DSR(fA1[1],avA[1],O); DSR(fA1[2],avA[2],O); DSR(fA1[3],avA[3],O); \
                    DSR(fA1[4],avA[4],O); DSR(fA1[5],avA[5],O); DSR(fA1[6],avA[6],O); DSR(fA1[7],avA[7],O); }while(0)
#define LDB(O)  do{ DSR(fB[0],avB[0],O); DSR(fB[1],avB[1],O); }while(0)

#define MM0(QN) do{ \
    _Pragma("unroll") \
    for (int kk = 0; kk < 2; ++kk) \
        _Pragma("unroll") \
        for (int im = 0; im < 4; ++im) \
            acc0[QN][im] = __builtin_amdgcn_mfma_f32_16x16x32_bf16( \
                fA0[im*2+kk], fB[kk], acc0[QN][im], 0, 0, 0); \
}while(0)
#define MM1(QN) do{ \
    _Pragma("unroll") \
    for (int kk = 0; kk < 2; ++kk) \
        _Pragma("unroll") \
        for (int im = 0; im < 4; ++im) \
            acc1[QN][im] = __builtin_amdgcn_mfma_f32_16x16x32_bf16( \
                fA1[im*2+kk], fB[kk], acc1[QN][im], 0, 0, 0); \
}while(0)

#define STG_A(BF,HH,KS) do{ \
    __builtin_amdgcn_global_load_lds((const AS1 void*)(pA##HH[0] + (size_t)(KS)*64), \
        (AS3 void*)&sA[BF][HH][wb8], 16, 0, 0); \
    __builtin_amdgcn_global_load_lds((const AS1 void*)(pA##HH[1] + (size_t)(KS)*64), \
        (AS3 void*)&sA[BF][HH][4096 + wb8], 16, 0, 0); \
}while(0)
#define STG_B(BF,QN,KS) \
    __builtin_amdgcn_global_load_lds((const AS1 void*)(pB[QN] + (size_t)(KS)*64), \
        (AS3 void*)&sB[BF][QN][wb8], 16, 0, 0)

#define PH_MID do{ __builtin_amdgcn_s_barrier(); \
    asm volatile("s_waitcnt lgkmcnt(0)" ::: "memory"); \
    __builtin_amdgcn_sched_barrier(0); \
    __builtin_amdgcn_s_setprio(1); }while(0)
#define PH_END do{ __builtin_amdgcn_s_setprio(0); \
    __builtin_amdgcn_sched_barrier(0); \
    __builtin_amdgcn_s_barrier(); }while(0)
#define PH_END_VMN(N) do{ __builtin_amdgcn_s_setprio(0); \
    __builtin_amdgcn_sched_barrier(0); \
    asm volatile("s_waitcnt vmcnt(" #N ")" ::: "memory"); \
    __builtin_amdgcn_s_barrier(); }while(0)

// One qm-half of the fused epilogue: qn-outer (weights loaded once per qn),
// 32 partials live, reduce+atomic at the end. ACC = acc0/acc1, QMOFF = 0/128.
#define EPI_HALF(ACC, QMOFF) do{ \
    float pa[4][4] = {}, pb[4][4] = {}; \
    _Pragma("unroll") \
    for (int qn = 0; qn < 3; ++qn) { \
        const int i = colBase + qn*64 + wc*16 + lm; \
        const float bwa = bw2[i], bwb = bw2[H + i]; \
        const float sca = sc2[i], scb = sc2[H + i]; \
        const float4* q0 = (const float4*)(sw2 + (size_t)i * 8); \
        const float4* q1 = (const float4*)(sw2 + (size_t)(H + i) * 8); \
        const float4 wa0 = q0[0], wa1 = q0[1]; \
        const float4 wb0 = q1[0], wb1 = q1[1]; \
        _Pragma("unroll") \
        for (int im = 0; im < 4; ++im) \
        _Pragma("unroll") \
        for (int rg = 0; rg < 4; ++rg) { \
            float u = gelu_fast(ACC[qn][im][rg]); \
            float f0v = silu_f(u); \
            float bb[8]; \
            kan_bases(u, bb); \
            float t0 = bb[0]*wa0.x + bb[1]*wa0.y + bb[2]*wa0.z + bb[3]*wa0.w \
                     + bb[4]*wa1.x + bb[5]*wa1.y + bb[6]*wa1.z + bb[7]*wa1.w; \
            float t1 = bb[0]*wb0.x + bb[1]*wb0.y + bb[2]*wb0.z + bb[3]*wb0.w \
                     + bb[4]*wb1.x + bb[5]*wb1.y + bb[6]*wb1.z + bb[7]*wb1.w; \
            pa[im][rg] += fmaf(f0v, bwa, sca * t0); \
            pb[im][rg] += fmaf(f0v, bwb, scb * t1); \
        } \
    } \
    _Pragma("unroll") \
    for (int im = 0; im < 4; ++im) \
    _Pragma("unroll") \
    for (int rg = 0; rg < 4; ++rg) { \
        float a0 = pa[im][rg], a1 = pb[im][rg]; \
        _Pragma("unroll") \
        for (int off = 8; off > 0; off >>= 1) { \
            a0 += __shfl_xor(a0, off, 64); \
            a1 += __shfl_xor(a1, off, 64); \
        } \
        if (lm == 0) { \
            const int row = rowBase + (QMOFF) + wr*64 + im*16 + quad*4 + rg; \
            atomicAdd(&outp[(size_t)row * 2 + 0], a0); \
            atomicAdd(&outp[(size_t)row * 2 + 1], a1); \
        } \
    } \
}while(0)

__global__ __launch_bounds__(512, 1) void kan1_fused(
    const unsigned short* __restrict__ F, const unsigned short* __restrict__ wp,
    const float* __restrict__ bw2, const float* __restrict__ sw2,
    const float* __restrict__ sc2, float* __restrict__ outp)
{
    __shared__ __align__(16) unsigned short sA[2][2][8192];  // [buf][half 128rows][128*64]
    __shared__ __align__(16) unsigned short sB[2][3][4096];  // [buf][third 64rows][64*64]

    const int b = blockIdx.x;                  // 0..255
    const int s = b >> 3;
    const int rowT = (b & 7) * 8 + (s >> 2);   // 0..63
    const int colT = s & 3;                    // 0..3
    const int rowBase = rowT * 256, colBase = colT * 192;

    const int t = threadIdx.x;
    const int lane = t & 63;
    const int quad = lane >> 4, lm = lane & 15, p7 = lane & 7;
    const int wv = t >> 6, wr = wv & 1, wc = wv >> 1;   // 2M x 4N wave grid

    const int rr = t >> 3;                    // 0..63
    const int slotx = (t & 7) ^ (rr & 7);
    const int wb8 = (t & 448) * 8;            // wave-uniform LDS elem base (wv*512)

    const unsigned short* pA0[2]; const unsigned short* pA1[2];
    const unsigned short* pB[3];
#pragma unroll
    for (int p = 0; p < 2; ++p) {
        pA0[p] = F + (size_t)(rowBase +       p*64 + rr) * KEXP + slotx*8;
        pA1[p] = F + (size_t)(rowBase + 128 + p*64 + rr) * KEXP + slotx*8;
    }
#pragma unroll
    for (int q = 0; q < 3; ++q)
        pB[q] = wp + (size_t)(colBase + q*64 + rr) * KEXP + slotx*8;

    unsigned int avA[8], avB[2];
    {
        unsigned int aB = (unsigned int)(size_t)(AS3 unsigned short*)&sA[0][0][0];
        unsigned int bB = (unsigned int)(size_t)(AS3 unsigned short*)&sB[0][0][0];
#pragma unroll
        for (int im = 0; im < 4; ++im)
#pragma unroll
            for (int kk = 0; kk < 2; ++kk)
                avA[im*2+kk] = aB + (unsigned)(((wr*64 + im*16 + lm)*64 + (((kk*4+quad)^p7)*8)) * 2);
#pragma unroll
        for (int kk = 0; kk < 2; ++kk)
            avB[kk] = bB + (unsigned)(((wc*16 + lm)*64 + (((kk*4+quad)^p7)*8)) * 2);
    }

    floatx4 acc0[3][4] = {};   // [qn][im], qm=0 rows
    floatx4 acc1[3][4] = {};   // qm=1 rows
    bhalf8 fA0[8], fA1[8], fB[2];

    // prologue: buf0 <- ks0 (7 loads), buf1 <- ks1 minus B2 (6 loads); retire 5
    STG_A(0,0,0); STG_A(0,1,0); STG_B(0,0,0); STG_B(0,1,0); STG_B(0,2,0);
    STG_A(1,0,1); STG_A(1,1,1); STG_B(1,0,1); STG_B(1,1,1);
    asm volatile("s_waitcnt vmcnt(8)" ::: "memory");
    __builtin_amdgcn_s_barrier();

#pragma unroll 1
    for (int i = 0; i < NITER; ++i) {
        const int k1 = 2*i + 1;
        const int k2 = (2*i + 2 > 107) ? 107 : 2*i + 2;
        const int k3 = (2*i + 3 > 107) ? 107 : 2*i + 3;
        // K-step 2i from buf0
        LDA0(0);     LDB(0);     STG_B(1,2,k1);               PH_MID; MM0(0);         PH_END_VMN(10);
        LDA1(16384);             STG_A(0,0,k2);               PH_MID; MM1(0);         PH_END_VMN(10);
        LDB(8192);               STG_A(0,1,k2);               PH_MID; MM1(1); MM0(1); PH_END_VMN(11);
        LDB(16384);              STG_B(0,0,k2); STG_B(0,1,k2);PH_MID; MM0(2); MM1(2); PH_END_VMN(8);
        // K-step 2i+1 from buf1
        LDA0(32768); LDB(24576); STG_B(0,2,k2);               PH_MID; MM0(0);         PH_END;
        LDA1(49152);             STG_A(1,0,k3);               PH_MID; MM1(0);         PH_END_VMN(10);
        LDB(32768);              STG_A(1,1,k3);               PH_MID; MM1(1); MM0(1); PH_END_VMN(11);
        LDB(40960);              STG_B(1,0,k3); STG_B(1,1,k3);PH_MID; MM0(2); MM1(2); PH_END_VMN(8);
    }

    // ---- fused layer-2 epilogue: two sequential low-pressure half-passes ----
    EPI_HALF(acc0, 0);
    EPI_HALF(acc1, 128);
}

extern "C" void kernel_launch(void* const* d_in, const int* in_sizes, int n_in,
                              void* d_out, int out_size, void* d_ws, size_t ws_size,
                              hipStream_t stream) {
    const float* hidden = (const float*)d_in[0];
    const float* bw1    = (const float*)d_in[1];
    const float* sw1    = (const float*)d_in[2];
    const float* sc1    = (const float*)d_in[3];
    const float* bw2    = (const float*)d_in[4];
    const float* sw2    = (const float*)d_in[5];
    const float* sc2    = (const float*)d_in[6];
    float* out = (float*)d_out;

    const size_t wp_elems = (size_t)H * KEXP;      // 10.6 MB bf16
    unsigned short* wp = (unsigned short*)d_ws;
    unsigned short* F  = wp + wp_elems;            // 226.5 MB bf16

    hipMemsetAsync(d_out, 0, (size_t)out_size, stream);   // graph-capturable
    prep_expand<<<6144 + H, 256, 0, stream>>>(hidden, bw1, sw1, sc1, wp, F);
    kan1_fused<<<256, 512, 0, stream>>>(F, wp, bw2, sw2, sc2, out);
}